// Round 2
// baseline (6206.813 us; speedup 1.0000x reference)
//
#include <hip/hip_runtime.h>
#include <hip/hip_bf16.h>
#include <math.h>

#define BB 64
#define JJ 16384
#define DD 32
#define HH 128
#define WW 4
#define EHH 256
#define CHUNK 128
#define CPB 8
#define NBLK (JJ / (CHUNK * CPB)) /* 16 */
#define PART_STRIDE 136
#define LN_EPS 1e-5f

// ---------------- Kernel 1: fused row-MLP + chunked online masked softmax ----------------
// Row split across wave pairs: waves 0,1 -> h[0:64], waves 2,3 -> h[64:128].
// Weight addresses are wave-uniform -> scalar loads (s_load), no VGPR cost.
__launch_bounds__(256, 2)
__global__ void pe_k1(const float* __restrict__ x, const int* __restrict__ mask,
                      const float* __restrict__ feat,
                      const float* __restrict__ w1, const float* __restrict__ b1,
                      const float* __restrict__ ln1g, const float* __restrict__ ln1b,
                      const float* __restrict__ w2, const float* __restrict__ b2,
                      const float* __restrict__ ln2g, const float* __restrict__ ln2b,
                      const float* __restrict__ gw1, const float* __restrict__ gb1,
                      const float* __restrict__ gw2, const float* __restrict__ gb2,
                      float* __restrict__ part)
{
    const int tid = threadIdx.x;
    const int cb = blockIdx.x, b = blockIdx.y;
    const int wv = tid >> 6, lane = tid & 63;
    const int hf = wv >> 1;                 // which half of the hidden vector
    const int r  = (wv & 1) * 64 + lane;    // row within chunk, 0..127

    __shared__ float rowbuf[CHUNK][33];     // feat staging -> s2 partials -> h_out
    __shared__ float p_lds[CHUNK][5];       // softmax numerators
    __shared__ float ln_s[2][CHUNK];
    __shared__ float ln_q[2][CHUNK];
    __shared__ float red_m[8];
    __shared__ float red_s[8];

    // accumulate-phase mapping (all 256 threads)
    const int aw = wv;                      // head 0..3
    const int ahalf = (tid >> 5) & 1;       // which 64-row half of the chunk
    const int ad = tid & 31;                // d 0..31

    float m_run = -1e30f, s_run = 0.f, accr = 0.f;

    for (int ch = 0; ch < CPB; ++ch) {
        const int jbase = (cb * CPB + ch) * CHUNK;

        // ---- stage feat rows into LDS (float4 coalesced, padded stride 33) ----
        {
            const float4* fs = (const float4*)(feat + (size_t)jbase * 32);
            #pragma unroll
            for (int i = 0; i < 4; ++i) {
                float4 v = fs[tid + i * 256];
                int e = (tid + i * 256) * 4;
                int rr = e >> 5, cc = e & 31;
                rowbuf[rr][cc]   = v.x; rowbuf[rr][cc+1] = v.y;
                rowbuf[rr][cc+2] = v.z; rowbuf[rr][cc+3] = v.w;
            }
        }
        __syncthreads();

        const int j = jbase + r;
        const float xin = x[(size_t)b * JJ + j];

        // ---- stage 1: (1+32) -> 64 outputs (this wave's half) ----
        float hb[64];
        {
            const float* w1h = w1 + hf * 64;
            const float* b1h = b1 + hf * 64;
            #pragma unroll
            for (int o = 0; o < 64; ++o) hb[o] = fmaf(w1h[o], xin, b1h[o]);
            for (int k = 1; k < 33; ++k) {
                const float f = rowbuf[r][k - 1];
                const float* wr = w1h + k * HH;
                #pragma unroll
                for (int o = 0; o < 64; ++o) hb[o] = fmaf(wr[o], f, hb[o]);
            }
        }
        // ---- LN1 (cross-wave-pair via LDS) + relu ----
        {
            float sp0=0,sp1=0,qp0=0,qp1=0;
            #pragma unroll
            for (int o = 0; o < 64; o += 2) {
                sp0 += hb[o];   sp1 += hb[o+1];
                qp0 = fmaf(hb[o],hb[o],qp0); qp1 = fmaf(hb[o+1],hb[o+1],qp1);
            }
            ln_s[hf][r] = sp0 + sp1;
            ln_q[hf][r] = qp0 + qp1;
        }
        __syncthreads();
        {
            const float st = ln_s[0][r] + ln_s[1][r];
            const float qt = ln_q[0][r] + ln_q[1][r];
            const float mu = st * (1.f/HH);
            float var = qt * (1.f/HH) - mu*mu;
            var = fmaxf(var, 0.f);
            const float rs = rsqrtf(var + LN_EPS);
            const float* gg = ln1g + hf*64;
            const float* bb = ln1b + hf*64;
            #pragma unroll
            for (int o = 0; o < 64; ++o)
                hb[o] = fmaxf(fmaf((hb[o]-mu)*rs, gg[o], bb[o]), 0.f);
        }

        // ---- stage 2 partials: this half's 64 k over all 32 outputs ----
        float p2[32];
        #pragma unroll
        for (int d = 0; d < 32; ++d) p2[d] = 0.f;
        {
            const float* w2h = w2 + hf * 64 * DD;
            for (int k = 0; k < 64; ++k) {
                const float hv = hb[k];
                const float* wr = w2h + k * DD;
                #pragma unroll
                for (int d = 0; d < 32; ++d) p2[d] = fmaf(hv, wr[d], p2[d]);
            }
        }
        // hf=1 publishes partials (rowbuf feat region is dead after LN1 sync)
        if (hf == 1) {
            #pragma unroll
            for (int d = 0; d < 32; ++d) rowbuf[r][d] = p2[d];
        }
        __syncthreads();

        float lg[WW];
        float maskf = 0.f;
        #pragma unroll
        for (int w = 0; w < WW; ++w) lg[w] = 0.f;

        if (hf == 0) {
            maskf = mask[(size_t)b * JJ + j] ? 1.f : 0.f;
            // combine halves + bias, LN2 + relu entirely in registers
            float v[DD];
            float s2 = 0.f, q2 = 0.f;
            #pragma unroll
            for (int d = 0; d < DD; ++d) {
                const float t = p2[d] + rowbuf[r][d] + b2[d];
                v[d] = t; s2 += t; q2 = fmaf(t, t, q2);
            }
            const float mu = s2 * (1.f/DD);
            float var = q2 * (1.f/DD) - mu*mu;
            var = fmaxf(var, 0.f);
            const float rs = rsqrtf(var + LN_EPS);
            float ho[DD];
            #pragma unroll
            for (int d = 0; d < DD; ++d) {
                const float t = fmaxf(fmaf((v[d]-mu)*rs, ln2g[d], ln2b[d]), 0.f);
                ho[d] = t;
                rowbuf[r][d] = t;       // h_out for the weighted-sum phase
            }

            // ---- stage 3: 32 -> 16 relu ----
            float g1v[16];
            #pragma unroll
            for (int o = 0; o < 16; ++o) g1v[o] = gb1[o];
            #pragma unroll
            for (int k = 0; k < DD; ++k) {
                #pragma unroll
                for (int o = 0; o < 16; ++o) g1v[o] = fmaf(ho[k], gw1[k*16+o], g1v[o]);
            }
            #pragma unroll
            for (int o = 0; o < 16; ++o) g1v[o] = fmaxf(g1v[o], 0.f);

            // ---- stage 4: 16 -> 4, clip ----
            #pragma unroll
            for (int w = 0; w < WW; ++w) lg[w] = gb2[w];
            #pragma unroll
            for (int k = 0; k < 16; ++k) {
                #pragma unroll
                for (int w = 0; w < WW; ++w) lg[w] = fmaf(g1v[k], gw2[k*WW+w], lg[w]);
            }
            #pragma unroll
            for (int w = 0; w < WW; ++w) lg[w] = fminf(fmaxf(lg[w], -10.f), 10.f);

            // ---- chunk masked max: shfl within wave (64 rows), combine 2 waves ----
            float lm[WW];
            #pragma unroll
            for (int w = 0; w < WW; ++w) lm[w] = (maskf > 0.f) ? lg[w] : -1e30f;
            #pragma unroll
            for (int off = 32; off > 0; off >>= 1) {
                #pragma unroll
                for (int w = 0; w < WW; ++w) lm[w] = fmaxf(lm[w], __shfl_xor(lm[w], off, 64));
            }
            if (lane == 0) {
                #pragma unroll
                for (int w = 0; w < WW; ++w) red_m[wv*4+w] = lm[w];
            }
        }
        __syncthreads();

        float m_c[WW];
        #pragma unroll
        for (int w = 0; w < WW; ++w) m_c[w] = fmaxf(red_m[w], red_m[4+w]);

        if (hf == 0) {
            float ps[WW];
            #pragma unroll
            for (int w = 0; w < WW; ++w) {
                const float pv = maskf * __expf(fminf(lg[w] - m_c[w], 0.f));
                p_lds[r][w] = pv;
                ps[w] = pv;
            }
            #pragma unroll
            for (int off = 32; off > 0; off >>= 1) {
                #pragma unroll
                for (int w = 0; w < WW; ++w) ps[w] += __shfl_xor(ps[w], off, 64);
            }
            if (lane == 0) {
                #pragma unroll
                for (int w = 0; w < WW; ++w) red_s[wv*4+w] = ps[w];
            }
        }
        __syncthreads();

        // ---- online merge into running (m,s,acc): all 256 threads dot 64 rows ----
        {
            const float s_c = red_s[aw] + red_s[4+aw];
            const float mc  = m_c[aw];
            const int jb0 = ahalf * 64;
            float dot = 0.f;
            #pragma unroll 4
            for (int jj = 0; jj < 64; ++jj)
                dot = fmaf(p_lds[jb0+jj][aw], rowbuf[jb0+jj][ad], dot);
            dot += __shfl_xor(dot, 32, 64);
            const float mn = fmaxf(m_run, mc);
            const float ea = __expf(m_run - mn);
            const float eb = __expf(mc - mn);
            if (ahalf == 0) {
                accr  = fmaf(accr,  ea, dot * eb);
                s_run = fmaf(s_run, ea, s_c * eb);
                m_run = mn;
            }
        }
        __syncthreads();
    }

    if (ahalf == 0) {
        float* pp = part + (size_t)(b * NBLK + cb) * PART_STRIDE;
        if (ad == 0) { pp[aw] = m_run; pp[4 + aw] = s_run; }
        pp[8 + aw*32 + ad] = accr;
    }
}

// ---------------- Kernel 2: merge partials + per-batch encoder head ----------------
__global__ void pe_k2(const float* __restrict__ part,
                      const float* __restrict__ cw, const float* __restrict__ cb_,
                      const float* __restrict__ cg, const float* __restrict__ cbn,
                      const float* __restrict__ ew1, const float* __restrict__ eb1,
                      const float* __restrict__ eg1, const float* __restrict__ ebn1,
                      const float* __restrict__ ew2, const float* __restrict__ eb2,
                      const float* __restrict__ eg2, const float* __restrict__ ebn2,
                      float* __restrict__ out)
{
    const int b = blockIdx.x, tid = threadIdx.x;
    const int w = tid >> 5, d = tid & 31;
    __shared__ float hs[128];
    __shared__ float cbuf[32];
    __shared__ float ebuf[256];
    __shared__ float obuf[64];

    // merge per-block online-softmax partials
    float m = -1e30f, s = 0.f, a = 0.f;
    for (int c = 0; c < NBLK; ++c) {
        const float* pp = part + (size_t)(b * NBLK + c) * PART_STRIDE;
        const float mc = pp[w], sc = pp[4 + w], ac = pp[8 + w*32 + d];
        const float mn = fmaxf(m, mc);
        const float e0 = __expf(m - mn), e1v = __expf(mc - mn);
        a = fmaf(a, e0, ac * e1v);
        s = fmaf(s, e0, sc * e1v);
        m = mn;
    }
    hs[w*32 + d] = a / fmaxf(s, 1e-30f);
    const bool has = (s > 0.f);
    __syncthreads();

    // combined = relu(LN(hs @ c_w + c_b)); c = has ? combined : 0
    if (tid < 32) {
        float acc = cb_[tid];
        for (int k = 0; k < 128; ++k) acc = fmaf(hs[k], cw[k*32 + tid], acc);
        cbuf[tid] = acc;
    }
    __syncthreads();
    {
        float mu = 0.f, sq = 0.f;
        for (int k = 0; k < 32; ++k) { float v = cbuf[k]; mu += v; sq = fmaf(v, v, sq); }
        mu *= (1.f/32);
        float var = fmaxf(sq*(1.f/32) - mu*mu, 0.f);
        const float rs = rsqrtf(var + LN_EPS);
        __syncthreads();
        if (tid < 32) {
            float v = (cbuf[tid] - mu) * rs;
            v = fmaxf(fmaf(v, cg[tid], cbn[tid]), 0.f);
            cbuf[tid] = has ? v : 0.f;
        }
    }
    __syncthreads();

    // e1 = relu(LN(c @ e_w1 + e_b1))   (32 -> 256)
    #pragma unroll
    for (int r = 0; r < 2; ++r) {
        const int o = tid + r*128;
        float acc = eb1[o];
        for (int k = 0; k < 32; ++k) acc = fmaf(cbuf[k], ew1[k*EHH + o], acc);
        ebuf[o] = acc;
    }
    __syncthreads();
    {
        float mu = 0.f, sq = 0.f;
        for (int k = 0; k < 256; ++k) { float v = ebuf[k]; mu += v; sq = fmaf(v, v, sq); }
        mu *= (1.f/256);
        float var = fmaxf(sq*(1.f/256) - mu*mu, 0.f);
        const float rs = rsqrtf(var + LN_EPS);
        __syncthreads();
        #pragma unroll
        for (int r = 0; r < 2; ++r) {
            const int o = tid + r*128;
            float v = (ebuf[o] - mu) * rs;
            ebuf[o] = fmaxf(fmaf(v, eg1[o], ebn1[o]), 0.f);
        }
    }
    __syncthreads();

    // mu_logvar = relu(LN(e1 @ e_w2 + e_b2))  (256 -> 64), split and store
    if (tid < 64) {
        float acc = eb2[tid];
        for (int k = 0; k < 256; ++k) acc = fmaf(ebuf[k], ew2[k*64 + tid], acc);
        obuf[tid] = acc;
    }
    __syncthreads();
    {
        float mu = 0.f, sq = 0.f;
        for (int k = 0; k < 64; ++k) { float v = obuf[k]; mu += v; sq = fmaf(v, v, sq); }
        mu *= (1.f/64);
        float var = fmaxf(sq*(1.f/64) - mu*mu, 0.f);
        const float rs = rsqrtf(var + LN_EPS);
        if (tid < 64) {
            float v = (obuf[tid] - mu) * rs;
            v = fmaxf(fmaf(v, eg2[tid], ebn2[tid]), 0.f);
            if (tid < 32) out[(size_t)b*32 + tid] = v;                      // mu
            else          out[(size_t)BB*32 + (size_t)b*32 + (tid-32)] = v; // logvar
        }
    }
}

extern "C" void kernel_launch(void* const* d_in, const int* in_sizes, int n_in,
                              void* d_out, int out_size, void* d_ws, size_t ws_size,
                              hipStream_t stream) {
    (void)in_sizes; (void)n_in; (void)out_size; (void)ws_size;
    const float* x     = (const float*)d_in[0];
    const int*   mask  = (const int*)  d_in[1];
    const float* feat  = (const float*)d_in[2];
    const float* h_w1  = (const float*)d_in[3];
    const float* h_b1  = (const float*)d_in[4];
    const float* h_l1g = (const float*)d_in[5];
    const float* h_l1b = (const float*)d_in[6];
    const float* h_w2  = (const float*)d_in[7];
    const float* h_b2  = (const float*)d_in[8];
    const float* h_l2g = (const float*)d_in[9];
    const float* h_l2b = (const float*)d_in[10];
    const float* g_w1  = (const float*)d_in[11];
    const float* g_b1  = (const float*)d_in[12];
    const float* g_w2  = (const float*)d_in[13];
    const float* g_b2  = (const float*)d_in[14];
    const float* c_w   = (const float*)d_in[15];
    const float* c_b   = (const float*)d_in[16];
    const float* c_lg  = (const float*)d_in[17];
    const float* c_lb  = (const float*)d_in[18];
    const float* e_w1  = (const float*)d_in[19];
    const float* e_b1  = (const float*)d_in[20];
    const float* e_l1g = (const float*)d_in[21];
    const float* e_l1b = (const float*)d_in[22];
    const float* e_w2  = (const float*)d_in[23];
    const float* e_b2  = (const float*)d_in[24];
    const float* e_l2g = (const float*)d_in[25];
    const float* e_l2b = (const float*)d_in[26];

    float* part = (float*)d_ws;
    float* out  = (float*)d_out;

    dim3 g1(NBLK, BB);
    pe_k1<<<g1, dim3(256), 0, stream>>>(x, mask, feat,
                                        h_w1, h_b1, h_l1g, h_l1b,
                                        h_w2, h_b2, h_l2g, h_l2b,
                                        g_w1, g_b1, g_w2, g_b2, part);
    pe_k2<<<dim3(BB), dim3(128), 0, stream>>>(part,
                                              c_w, c_b, c_lg, c_lb,
                                              e_w1, e_b1, e_l1g, e_l1b,
                                              e_w2, e_b2, e_l2g, e_l2b, out);
}

// Round 3
// 5324.678 us; speedup vs baseline: 1.1657x; 1.1657x over previous
//
#include <hip/hip_runtime.h>
#include <hip/hip_bf16.h>
#include <math.h>

#define BB 64
#define JJ 16384
#define DD 32
#define HH 128
#define WW 4
#define EHH 256
#define CHUNK 128
#define CPB 8
#define NBLK (JJ / (CHUNK * CPB)) /* 16 */
#define PART_STRIDE 136
#define LN_EPS 1e-5f

// ---------------- Kernel 1: fused row-MLP + chunked online masked softmax ----------------
// Row split across wave pairs: waves 0,1 -> h[0:64], waves 2,3 -> h[64:128].
// ALL register-array indices are compile-time constants (rule #20): the
// stage-2 k-loop is fully unrolled so hb[]/p2[] stay in VGPRs, not scratch.
__launch_bounds__(256, 2)
__global__ void pe_k1(const float* __restrict__ x, const int* __restrict__ mask,
                      const float* __restrict__ feat,
                      const float* __restrict__ w1, const float* __restrict__ b1,
                      const float* __restrict__ ln1g, const float* __restrict__ ln1b,
                      const float* __restrict__ w2, const float* __restrict__ b2,
                      const float* __restrict__ ln2g, const float* __restrict__ ln2b,
                      const float* __restrict__ gw1, const float* __restrict__ gb1,
                      const float* __restrict__ gw2, const float* __restrict__ gb2,
                      float* __restrict__ part)
{
    const int tid = threadIdx.x;
    const int cb = blockIdx.x, b = blockIdx.y;
    const int wv = tid >> 6, lane = tid & 63;
    const int hf = wv >> 1;                 // which half of the hidden vector
    const int r  = (wv & 1) * 64 + lane;    // row within chunk, 0..127

    __shared__ float rowbuf[CHUNK][33];     // feat staging -> s2 partials -> h_out
    __shared__ float p_lds[CHUNK][5];       // softmax numerators
    __shared__ float ln_s[2][CHUNK];
    __shared__ float ln_q[2][CHUNK];
    __shared__ float red_m[8];
    __shared__ float red_s[8];

    // accumulate-phase mapping (all 256 threads)
    const int aw = wv;                      // head 0..3
    const int ahalf = (tid >> 5) & 1;       // which 64-row half of the chunk
    const int ad = tid & 31;                // d 0..31

    float m_run = -1e30f, s_run = 0.f, accr = 0.f;

    for (int ch = 0; ch < CPB; ++ch) {
        const int jbase = (cb * CPB + ch) * CHUNK;

        // ---- stage feat rows into LDS (float4 coalesced, padded stride 33) ----
        {
            const float4* fs = (const float4*)(feat + (size_t)jbase * 32);
            #pragma unroll
            for (int i = 0; i < 4; ++i) {
                float4 v = fs[tid + i * 256];
                int e = (tid + i * 256) * 4;
                int rr = e >> 5, cc = e & 31;
                rowbuf[rr][cc]   = v.x; rowbuf[rr][cc+1] = v.y;
                rowbuf[rr][cc+2] = v.z; rowbuf[rr][cc+3] = v.w;
            }
        }
        __syncthreads();

        const int j = jbase + r;
        const float xin = x[(size_t)b * JJ + j];

        // ---- stage 1: (1+32) -> 64 outputs (this wave's half) ----
        float hb[64];
        {
            const float* w1h = w1 + hf * 64;
            const float* b1h = b1 + hf * 64;
            #pragma unroll
            for (int o = 0; o < 64; ++o) hb[o] = fmaf(w1h[o], xin, b1h[o]);
            for (int k = 1; k < 33; ++k) {
                const float f = rowbuf[r][k - 1];
                const float* wr = w1h + k * HH;
                #pragma unroll
                for (int o = 0; o < 64; ++o) hb[o] = fmaf(wr[o], f, hb[o]);
            }
        }
        // ---- LN1 (cross-wave-pair via LDS) + relu ----
        {
            float sp0=0,sp1=0,qp0=0,qp1=0;
            #pragma unroll
            for (int o = 0; o < 64; o += 2) {
                sp0 += hb[o];   sp1 += hb[o+1];
                qp0 = fmaf(hb[o],hb[o],qp0); qp1 = fmaf(hb[o+1],hb[o+1],qp1);
            }
            ln_s[hf][r] = sp0 + sp1;
            ln_q[hf][r] = qp0 + qp1;
        }
        __syncthreads();
        {
            const float st = ln_s[0][r] + ln_s[1][r];
            const float qt = ln_q[0][r] + ln_q[1][r];
            const float mu = st * (1.f/HH);
            float var = qt * (1.f/HH) - mu*mu;
            var = fmaxf(var, 0.f);
            const float rs = rsqrtf(var + LN_EPS);
            const float* gg = ln1g + hf*64;
            const float* bb = ln1b + hf*64;
            #pragma unroll
            for (int o = 0; o < 64; ++o)
                hb[o] = fmaxf(fmaf((hb[o]-mu)*rs, gg[o], bb[o]), 0.f);
        }

        // ---- stage 2 partials: this half's 64 k over all 32 outputs ----
        // FULLY unrolled: hb[k] and p2[d] must be static indices (else scratch).
        float p2[32];
        #pragma unroll
        for (int d = 0; d < 32; ++d) p2[d] = 0.f;
        {
            const float* w2h = w2 + hf * 64 * DD;
            #pragma unroll
            for (int k = 0; k < 64; ++k) {
                const float hv = hb[k];
                const float* wr = w2h + k * DD;
                #pragma unroll
                for (int d = 0; d < 32; ++d) p2[d] = fmaf(hv, wr[d], p2[d]);
            }
        }
        // hf=1 publishes partials (rowbuf feat region is dead after LN1 sync)
        if (hf == 1) {
            #pragma unroll
            for (int d = 0; d < 32; ++d) rowbuf[r][d] = p2[d];
        }
        __syncthreads();

        float lg[WW];
        float maskf = 0.f;
        #pragma unroll
        for (int w = 0; w < WW; ++w) lg[w] = 0.f;

        if (hf == 0) {
            maskf = mask[(size_t)b * JJ + j] ? 1.f : 0.f;
            // combine halves + bias, LN2 + relu entirely in registers
            float v[DD];
            float s2 = 0.f, q2 = 0.f;
            #pragma unroll
            for (int d = 0; d < DD; ++d) {
                const float t = p2[d] + rowbuf[r][d] + b2[d];
                v[d] = t; s2 += t; q2 = fmaf(t, t, q2);
            }
            const float mu = s2 * (1.f/DD);
            float var = q2 * (1.f/DD) - mu*mu;
            var = fmaxf(var, 0.f);
            const float rs = rsqrtf(var + LN_EPS);
            float ho[DD];
            #pragma unroll
            for (int d = 0; d < DD; ++d) {
                const float t = fmaxf(fmaf((v[d]-mu)*rs, ln2g[d], ln2b[d]), 0.f);
                ho[d] = t;
                rowbuf[r][d] = t;       // h_out for the weighted-sum phase
            }

            // ---- stage 3: 32 -> 16 relu ----
            float g1v[16];
            #pragma unroll
            for (int o = 0; o < 16; ++o) g1v[o] = gb1[o];
            #pragma unroll
            for (int k = 0; k < DD; ++k) {
                #pragma unroll
                for (int o = 0; o < 16; ++o) g1v[o] = fmaf(ho[k], gw1[k*16+o], g1v[o]);
            }
            #pragma unroll
            for (int o = 0; o < 16; ++o) g1v[o] = fmaxf(g1v[o], 0.f);

            // ---- stage 4: 16 -> 4, clip ----
            #pragma unroll
            for (int w = 0; w < WW; ++w) lg[w] = gb2[w];
            #pragma unroll
            for (int k = 0; k < 16; ++k) {
                #pragma unroll
                for (int w = 0; w < WW; ++w) lg[w] = fmaf(g1v[k], gw2[k*WW+w], lg[w]);
            }
            #pragma unroll
            for (int w = 0; w < WW; ++w) lg[w] = fminf(fmaxf(lg[w], -10.f), 10.f);

            // ---- chunk masked max: shfl within wave (64 rows), combine 2 waves ----
            float lm[WW];
            #pragma unroll
            for (int w = 0; w < WW; ++w) lm[w] = (maskf > 0.f) ? lg[w] : -1e30f;
            #pragma unroll
            for (int off = 32; off > 0; off >>= 1) {
                #pragma unroll
                for (int w = 0; w < WW; ++w) lm[w] = fmaxf(lm[w], __shfl_xor(lm[w], off, 64));
            }
            if (lane == 0) {
                #pragma unroll
                for (int w = 0; w < WW; ++w) red_m[wv*4+w] = lm[w];
            }
        }
        __syncthreads();

        float m_c[WW];
        #pragma unroll
        for (int w = 0; w < WW; ++w) m_c[w] = fmaxf(red_m[w], red_m[4+w]);

        if (hf == 0) {
            float ps[WW];
            #pragma unroll
            for (int w = 0; w < WW; ++w) {
                const float pv = maskf * __expf(fminf(lg[w] - m_c[w], 0.f));
                p_lds[r][w] = pv;
                ps[w] = pv;
            }
            #pragma unroll
            for (int off = 32; off > 0; off >>= 1) {
                #pragma unroll
                for (int w = 0; w < WW; ++w) ps[w] += __shfl_xor(ps[w], off, 64);
            }
            if (lane == 0) {
                #pragma unroll
                for (int w = 0; w < WW; ++w) red_s[wv*4+w] = ps[w];
            }
        }
        __syncthreads();

        // ---- online merge into running (m,s,acc): all 256 threads dot 64 rows ----
        {
            const float s_c = red_s[aw] + red_s[4+aw];
            const float mc  = m_c[aw];
            const int jb0 = ahalf * 64;
            float dot = 0.f;
            #pragma unroll 4
            for (int jj = 0; jj < 64; ++jj)
                dot = fmaf(p_lds[jb0+jj][aw], rowbuf[jb0+jj][ad], dot);
            dot += __shfl_xor(dot, 32, 64);
            const float mn = fmaxf(m_run, mc);
            const float ea = __expf(m_run - mn);
            const float eb = __expf(mc - mn);
            if (ahalf == 0) {
                accr  = fmaf(accr,  ea, dot * eb);
                s_run = fmaf(s_run, ea, s_c * eb);
                m_run = mn;
            }
        }
        __syncthreads();
    }

    if (ahalf == 0) {
        float* pp = part + (size_t)(b * NBLK + cb) * PART_STRIDE;
        if (ad == 0) { pp[aw] = m_run; pp[4 + aw] = s_run; }
        pp[8 + aw*32 + ad] = accr;
    }
}

// ---------------- Kernel 2: merge partials + per-batch encoder head ----------------
__global__ void pe_k2(const float* __restrict__ part,
                      const float* __restrict__ cw, const float* __restrict__ cb_,
                      const float* __restrict__ cg, const float* __restrict__ cbn,
                      const float* __restrict__ ew1, const float* __restrict__ eb1,
                      const float* __restrict__ eg1, const float* __restrict__ ebn1,
                      const float* __restrict__ ew2, const float* __restrict__ eb2,
                      const float* __restrict__ eg2, const float* __restrict__ ebn2,
                      float* __restrict__ out)
{
    const int b = blockIdx.x, tid = threadIdx.x;
    const int w = tid >> 5, d = tid & 31;
    __shared__ float hs[128];
    __shared__ float cbuf[32];
    __shared__ float ebuf[256];
    __shared__ float obuf[64];

    // merge per-block online-softmax partials
    float m = -1e30f, s = 0.f, a = 0.f;
    for (int c = 0; c < NBLK; ++c) {
        const float* pp = part + (size_t)(b * NBLK + c) * PART_STRIDE;
        const float mc = pp[w], sc = pp[4 + w], ac = pp[8 + w*32 + d];
        const float mn = fmaxf(m, mc);
        const float e0 = __expf(m - mn), e1v = __expf(mc - mn);
        a = fmaf(a, e0, ac * e1v);
        s = fmaf(s, e0, sc * e1v);
        m = mn;
    }
    hs[w*32 + d] = a / fmaxf(s, 1e-30f);
    const bool has = (s > 0.f);
    __syncthreads();

    // combined = relu(LN(hs @ c_w + c_b)); c = has ? combined : 0
    if (tid < 32) {
        float acc = cb_[tid];
        for (int k = 0; k < 128; ++k) acc = fmaf(hs[k], cw[k*32 + tid], acc);
        cbuf[tid] = acc;
    }
    __syncthreads();
    {
        float mu = 0.f, sq = 0.f;
        for (int k = 0; k < 32; ++k) { float v = cbuf[k]; mu += v; sq = fmaf(v, v, sq); }
        mu *= (1.f/32);
        float var = fmaxf(sq*(1.f/32) - mu*mu, 0.f);
        const float rs = rsqrtf(var + LN_EPS);
        __syncthreads();
        if (tid < 32) {
            float v = (cbuf[tid] - mu) * rs;
            v = fmaxf(fmaf(v, cg[tid], cbn[tid]), 0.f);
            cbuf[tid] = has ? v : 0.f;
        }
    }
    __syncthreads();

    // e1 = relu(LN(c @ e_w1 + e_b1))   (32 -> 256)
    #pragma unroll
    for (int r = 0; r < 2; ++r) {
        const int o = tid + r*128;
        float acc = eb1[o];
        for (int k = 0; k < 32; ++k) acc = fmaf(cbuf[k], ew1[k*EHH + o], acc);
        ebuf[o] = acc;
    }
    __syncthreads();
    {
        float mu = 0.f, sq = 0.f;
        for (int k = 0; k < 256; ++k) { float v = ebuf[k]; mu += v; sq = fmaf(v, v, sq); }
        mu *= (1.f/256);
        float var = fmaxf(sq*(1.f/256) - mu*mu, 0.f);
        const float rs = rsqrtf(var + LN_EPS);
        __syncthreads();
        #pragma unroll
        for (int r = 0; r < 2; ++r) {
            const int o = tid + r*128;
            float v = (ebuf[o] - mu) * rs;
            ebuf[o] = fmaxf(fmaf(v, eg1[o], ebn1[o]), 0.f);
        }
    }
    __syncthreads();

    // mu_logvar = relu(LN(e1 @ e_w2 + e_b2))  (256 -> 64), split and store
    if (tid < 64) {
        float acc = eb2[tid];
        for (int k = 0; k < 256; ++k) acc = fmaf(ebuf[k], ew2[k*64 + tid], acc);
        obuf[tid] = acc;
    }
    __syncthreads();
    {
        float mu = 0.f, sq = 0.f;
        for (int k = 0; k < 64; ++k) { float v = obuf[k]; mu += v; sq = fmaf(v, v, sq); }
        mu *= (1.f/64);
        float var = fmaxf(sq*(1.f/64) - mu*mu, 0.f);
        const float rs = rsqrtf(var + LN_EPS);
        if (tid < 64) {
            float v = (obuf[tid] - mu) * rs;
            v = fmaxf(fmaf(v, eg2[tid], ebn2[tid]), 0.f);
            if (tid < 32) out[(size_t)b*32 + tid] = v;                      // mu
            else          out[(size_t)BB*32 + (size_t)b*32 + (tid-32)] = v; // logvar
        }
    }
}

extern "C" void kernel_launch(void* const* d_in, const int* in_sizes, int n_in,
                              void* d_out, int out_size, void* d_ws, size_t ws_size,
                              hipStream_t stream) {
    (void)in_sizes; (void)n_in; (void)out_size; (void)ws_size;
    const float* x     = (const float*)d_in[0];
    const int*   mask  = (const int*)  d_in[1];
    const float* feat  = (const float*)d_in[2];
    const float* h_w1  = (const float*)d_in[3];
    const float* h_b1  = (const float*)d_in[4];
    const float* h_l1g = (const float*)d_in[5];
    const float* h_l1b = (const float*)d_in[6];
    const float* h_w2  = (const float*)d_in[7];
    const float* h_b2  = (const float*)d_in[8];
    const float* h_l2g = (const float*)d_in[9];
    const float* h_l2b = (const float*)d_in[10];
    const float* g_w1  = (const float*)d_in[11];
    const float* g_b1  = (const float*)d_in[12];
    const float* g_w2  = (const float*)d_in[13];
    const float* g_b2  = (const float*)d_in[14];
    const float* c_w   = (const float*)d_in[15];
    const float* c_b   = (const float*)d_in[16];
    const float* c_lg  = (const float*)d_in[17];
    const float* c_lb  = (const float*)d_in[18];
    const float* e_w1  = (const float*)d_in[19];
    const float* e_b1  = (const float*)d_in[20];
    const float* e_l1g = (const float*)d_in[21];
    const float* e_l1b = (const float*)d_in[22];
    const float* e_w2  = (const float*)d_in[23];
    const float* e_b2  = (const float*)d_in[24];
    const float* e_l2g = (const float*)d_in[25];
    const float* e_l2b = (const float*)d_in[26];

    float* part = (float*)d_ws;
    float* out  = (float*)d_out;

    dim3 g1(NBLK, BB);
    pe_k1<<<g1, dim3(256), 0, stream>>>(x, mask, feat,
                                        h_w1, h_b1, h_l1g, h_l1b,
                                        h_w2, h_b2, h_l2g, h_l2b,
                                        g_w1, g_b1, g_w2, g_b2, part);
    pe_k2<<<dim3(BB), dim3(128), 0, stream>>>(part,
                                              c_w, c_b, c_lg, c_lb,
                                              e_w1, e_b1, e_l1g, e_l1b,
                                              e_w2, e_b2, e_l2g, e_l2b, out);
}

// Round 4
// 1590.651 us; speedup vs baseline: 3.9021x; 3.3475x over previous
//
#include <hip/hip_runtime.h>
#include <hip/hip_bf16.h>
#include <math.h>

#define BB 64
#define JJ 16384
#define DD 32
#define HH 128
#define WW 4
#define EHH 256
#define CHUNK 64
#define CPB 16
#define NBLK 16              /* JJ/(CHUNK*CPB) */
#define PART_STRIDE 136
#define LN_EPS 1e-5f

// stage-1 FMA block: quad Q of w1, rows f0/f1 -> hb0/hb1[B..B+3]
#define S1Q(Q,B) \
  hb0[B+0]=fmaf((Q).x,f0,hb0[B+0]); hb1[B+0]=fmaf((Q).x,f1,hb1[B+0]); \
  hb0[B+1]=fmaf((Q).y,f0,hb0[B+1]); hb1[B+1]=fmaf((Q).y,f1,hb1[B+1]); \
  hb0[B+2]=fmaf((Q).z,f0,hb0[B+2]); hb1[B+2]=fmaf((Q).z,f1,hb1[B+2]); \
  hb0[B+3]=fmaf((Q).w,f0,hb0[B+3]); hb1[B+3]=fmaf((Q).w,f1,hb1[B+3]);

#define G1Q(Q,B) \
  g1a[B+0]=fmaf(h0v,(Q).x,g1a[B+0]); g1b[B+0]=fmaf(h1v,(Q).x,g1b[B+0]); \
  g1a[B+1]=fmaf(h0v,(Q).y,g1a[B+1]); g1b[B+1]=fmaf(h1v,(Q).y,g1b[B+1]); \
  g1a[B+2]=fmaf(h0v,(Q).z,g1a[B+2]); g1b[B+2]=fmaf(h1v,(Q).z,g1b[B+2]); \
  g1a[B+3]=fmaf(h0v,(Q).w,g1a[B+3]); g1b[B+3]=fmaf(h1v,(Q).w,g1b[B+3]);

// ---------------- Kernel 1 ----------------
// Thread (rg, sg): rg = tid>>3 (2 rows), sg = tid&7.
// Stage1: sg = 16-wide hidden segment  (hb = 2x16 regs, max live array)
// Stage2: sg = 4-wide output segment   (acc = 2x4 regs)
// All cross-seg reductions are intra-wave shfl_xor over lane bits 0..2.
__launch_bounds__(256, 3)
__global__ void pe_k1(const float* __restrict__ x, const int* __restrict__ mask,
                      const float* __restrict__ feat,
                      const float* __restrict__ w1, const float* __restrict__ b1,
                      const float* __restrict__ ln1g, const float* __restrict__ ln1b,
                      const float* __restrict__ w2, const float* __restrict__ b2,
                      const float* __restrict__ ln2g, const float* __restrict__ ln2b,
                      const float* __restrict__ gw1, const float* __restrict__ gb1,
                      const float* __restrict__ gw2, const float* __restrict__ gb2,
                      float* __restrict__ part)
{
    const int tid = threadIdx.x;
    const int cb = blockIdx.x, b = blockIdx.y;
    const int rg = tid >> 3, sg = tid & 7;
    const int r0 = rg * 2, r1 = r0 + 1;
    const int wv = tid >> 6, lane = tid & 63;

    __shared__ float in_lds[CHUNK][37];   // col0 = x, cols 1..32 = feat
    __shared__ float hlds[CHUNK][37];     // normalized h (128 per row, cols 0..127 across rows? no: [row][k] k<... )
    __shared__ float holds[CHUNK][37];    // h_out (32 per row)
    __shared__ float hk[CHUNK][132];      // h per row, 128 cols + pad4 (16B-aligned rows)
    __shared__ float mask_lds[CHUNK];
    __shared__ float p_lds[CHUNK][5];
    __shared__ float red_m[4][4];
    __shared__ float red_s[4][4];

    const int aw = tid >> 6, ahalf = (tid >> 5) & 1, ad = tid & 31;

    float m_run = -1e30f, s_run = 0.f, accr = 0.f;

    for (int ch = 0; ch < CPB; ++ch) {
        const int jbase = (cb * CPB + ch) * CHUNK;

        // ---- stage inputs: feat (float4), x, mask ----
        {
            const float4* fs = (const float4*)(feat + (size_t)jbase * 32);
            #pragma unroll
            for (int i = 0; i < 2; ++i) {
                const int t = tid + i * 256;
                const float4 v = fs[t];
                const int row = t >> 3, c0 = (t & 7) * 4 + 1;
                in_lds[row][c0]   = v.x; in_lds[row][c0+1] = v.y;
                in_lds[row][c0+2] = v.z; in_lds[row][c0+3] = v.w;
            }
            if (tid < CHUNK) in_lds[tid][0] = x[(size_t)b * JJ + jbase + tid];
            else if (tid < 2*CHUNK)
                mask_lds[tid-CHUNK] = mask[(size_t)b * JJ + jbase + (tid-CHUNK)] ? 1.f : 0.f;
        }
        __syncthreads();

        // ---- stage 1: (1+32) -> hidden[ sg*16 .. +15 ] for rows r0,r1 ----
        float hb0[16], hb1[16];
        {
            const float* w1s = w1 + sg * 16;
            const float4 bq0 = *(const float4*)(b1 + sg*16);
            const float4 bq1 = *(const float4*)(b1 + sg*16 + 4);
            const float4 bq2 = *(const float4*)(b1 + sg*16 + 8);
            const float4 bq3 = *(const float4*)(b1 + sg*16 + 12);
            hb0[0]=bq0.x; hb0[1]=bq0.y; hb0[2]=bq0.z; hb0[3]=bq0.w;
            hb0[4]=bq1.x; hb0[5]=bq1.y; hb0[6]=bq1.z; hb0[7]=bq1.w;
            hb0[8]=bq2.x; hb0[9]=bq2.y; hb0[10]=bq2.z; hb0[11]=bq2.w;
            hb0[12]=bq3.x; hb0[13]=bq3.y; hb0[14]=bq3.z; hb0[15]=bq3.w;
            #pragma unroll
            for (int o = 0; o < 16; ++o) hb1[o] = hb0[o];
            #pragma unroll 3
            for (int k = 0; k < 33; ++k) {
                const float f0 = in_lds[r0][k], f1 = in_lds[r1][k];
                const float* wr = w1s + k * HH;
                const float4 q0 = *(const float4*)(wr);
                const float4 q1 = *(const float4*)(wr + 4);
                const float4 q2 = *(const float4*)(wr + 8);
                const float4 q3 = *(const float4*)(wr + 12);
                S1Q(q0,0) S1Q(q1,4) S1Q(q2,8) S1Q(q3,12)
            }
        }
        // ---- LN1 + relu (row stats via 8-lane butterfly) ----
        {
            float s0=0.f,q0=0.f,s1=0.f,q1=0.f;
            #pragma unroll
            for (int o = 0; o < 16; ++o) {
                s0 += hb0[o]; q0 = fmaf(hb0[o],hb0[o],q0);
                s1 += hb1[o]; q1 = fmaf(hb1[o],hb1[o],q1);
            }
            #pragma unroll
            for (int st = 1; st < 8; st <<= 1) {
                s0 += __shfl_xor(s0, st, 64); q0 += __shfl_xor(q0, st, 64);
                s1 += __shfl_xor(s1, st, 64); q1 += __shfl_xor(q1, st, 64);
            }
            const float mu0 = s0 * (1.f/HH);
            const float rs0 = rsqrtf(fmaxf(q0*(1.f/HH) - mu0*mu0, 0.f) + LN_EPS);
            const float mu1 = s1 * (1.f/HH);
            const float rs1 = rsqrtf(fmaxf(q1*(1.f/HH) - mu1*mu1, 0.f) + LN_EPS);
            const float4 g0 = *(const float4*)(ln1g + sg*16);
            const float4 g1_ = *(const float4*)(ln1g + sg*16 + 4);
            const float4 g2 = *(const float4*)(ln1g + sg*16 + 8);
            const float4 g3 = *(const float4*)(ln1g + sg*16 + 12);
            const float4 t0 = *(const float4*)(ln1b + sg*16);
            const float4 t1 = *(const float4*)(ln1b + sg*16 + 4);
            const float4 t2 = *(const float4*)(ln1b + sg*16 + 8);
            const float4 t3 = *(const float4*)(ln1b + sg*16 + 12);
            float gg[16], bb[16];
            gg[0]=g0.x; gg[1]=g0.y; gg[2]=g0.z; gg[3]=g0.w;
            gg[4]=g1_.x; gg[5]=g1_.y; gg[6]=g1_.z; gg[7]=g1_.w;
            gg[8]=g2.x; gg[9]=g2.y; gg[10]=g2.z; gg[11]=g2.w;
            gg[12]=g3.x; gg[13]=g3.y; gg[14]=g3.z; gg[15]=g3.w;
            bb[0]=t0.x; bb[1]=t0.y; bb[2]=t0.z; bb[3]=t0.w;
            bb[4]=t1.x; bb[5]=t1.y; bb[6]=t1.z; bb[7]=t1.w;
            bb[8]=t2.x; bb[9]=t2.y; bb[10]=t2.z; bb[11]=t2.w;
            bb[12]=t3.x; bb[13]=t3.y; bb[14]=t3.z; bb[15]=t3.w;
            #pragma unroll
            for (int o = 0; o < 16; ++o) {
                const float v0 = fmaxf(fmaf((hb0[o]-mu0)*rs0, gg[o], bb[o]), 0.f);
                const float v1 = fmaxf(fmaf((hb1[o]-mu1)*rs1, gg[o], bb[o]), 0.f);
                hk[r0][sg*16+o] = v0;
                hk[r1][sg*16+o] = v1;
            }
        }
        // hk producers/consumers share the same 8-lane group -> no barrier needed

        // ---- stage 2: h(128) -> d[ sg*4 .. +3 ] for rows r0,r1 ----
        float ac0[4] = {0.f,0.f,0.f,0.f}, ac1[4] = {0.f,0.f,0.f,0.f};
        {
            const float* w2s = w2 + sg * 4;
            #pragma unroll 4
            for (int k = 0; k < HH; ++k) {
                const float h0 = hk[r0][k], h1 = hk[r1][k];
                const float4 q = *(const float4*)(w2s + k * DD);
                ac0[0]=fmaf(h0,q.x,ac0[0]); ac1[0]=fmaf(h1,q.x,ac1[0]);
                ac0[1]=fmaf(h0,q.y,ac0[1]); ac1[1]=fmaf(h1,q.y,ac1[1]);
                ac0[2]=fmaf(h0,q.z,ac0[2]); ac1[2]=fmaf(h1,q.z,ac1[2]);
                ac0[3]=fmaf(h0,q.w,ac0[3]); ac1[3]=fmaf(h1,q.w,ac1[3]);
            }
            const float4 bq = *(const float4*)(b2 + sg*4);
            ac0[0]+=bq.x; ac0[1]+=bq.y; ac0[2]+=bq.z; ac0[3]+=bq.w;
            ac1[0]+=bq.x; ac1[1]+=bq.y; ac1[2]+=bq.z; ac1[3]+=bq.w;
        }
        // ---- LN2 + relu ----
        float ho0[4], ho1[4];
        {
            float s0 = ac0[0]+ac0[1]+ac0[2]+ac0[3];
            float s1 = ac1[0]+ac1[1]+ac1[2]+ac1[3];
            float q0 = ac0[0]*ac0[0]+ac0[1]*ac0[1]+ac0[2]*ac0[2]+ac0[3]*ac0[3];
            float q1 = ac1[0]*ac1[0]+ac1[1]*ac1[1]+ac1[2]*ac1[2]+ac1[3]*ac1[3];
            #pragma unroll
            for (int st = 1; st < 8; st <<= 1) {
                s0 += __shfl_xor(s0, st, 64); q0 += __shfl_xor(q0, st, 64);
                s1 += __shfl_xor(s1, st, 64); q1 += __shfl_xor(q1, st, 64);
            }
            const float mu0 = s0 * (1.f/DD);
            const float rs0 = rsqrtf(fmaxf(q0*(1.f/DD) - mu0*mu0, 0.f) + LN_EPS);
            const float mu1 = s1 * (1.f/DD);
            const float rs1 = rsqrtf(fmaxf(q1*(1.f/DD) - mu1*mu1, 0.f) + LN_EPS);
            const float4 gq = *(const float4*)(ln2g + sg*4);
            const float4 tq = *(const float4*)(ln2b + sg*4);
            ho0[0]=fmaxf(fmaf((ac0[0]-mu0)*rs0, gq.x, tq.x),0.f);
            ho0[1]=fmaxf(fmaf((ac0[1]-mu0)*rs0, gq.y, tq.y),0.f);
            ho0[2]=fmaxf(fmaf((ac0[2]-mu0)*rs0, gq.z, tq.z),0.f);
            ho0[3]=fmaxf(fmaf((ac0[3]-mu0)*rs0, gq.w, tq.w),0.f);
            ho1[0]=fmaxf(fmaf((ac1[0]-mu1)*rs1, gq.x, tq.x),0.f);
            ho1[1]=fmaxf(fmaf((ac1[1]-mu1)*rs1, gq.y, tq.y),0.f);
            ho1[2]=fmaxf(fmaf((ac1[2]-mu1)*rs1, gq.z, tq.z),0.f);
            ho1[3]=fmaxf(fmaf((ac1[3]-mu1)*rs1, gq.w, tq.w),0.f);
            #pragma unroll
            for (int i = 0; i < 4; ++i) {
                holds[r0][sg*4+i] = ho0[i];
                holds[r1][sg*4+i] = ho1[i];
            }
        }

        // ---- stage 3: 32 -> 16 (partials over own 4 k, butterfly sum) ----
        float g1a[16], g1b[16];
        #pragma unroll
        for (int o = 0; o < 16; ++o) { g1a[o]=0.f; g1b[o]=0.f; }
        #pragma unroll
        for (int kk = 0; kk < 4; ++kk) {
            const float h0v = ho0[kk], h1v = ho1[kk];
            const float* gr = gw1 + (sg*4+kk)*16;
            const float4 p0 = *(const float4*)(gr);
            const float4 p1 = *(const float4*)(gr + 4);
            const float4 p2 = *(const float4*)(gr + 8);
            const float4 p3 = *(const float4*)(gr + 12);
            G1Q(p0,0) G1Q(p1,4) G1Q(p2,8) G1Q(p3,12)
        }
        #pragma unroll
        for (int st = 1; st < 8; st <<= 1) {
            #pragma unroll
            for (int o = 0; o < 16; ++o) {
                g1a[o] += __shfl_xor(g1a[o], st, 64);
                g1b[o] += __shfl_xor(g1b[o], st, 64);
            }
        }
        #pragma unroll
        for (int o = 0; o < 16; ++o) {
            g1a[o] = fmaxf(g1a[o] + gb1[o], 0.f);
            g1b[o] = fmaxf(g1b[o] + gb1[o], 0.f);
        }

        // ---- stage 4: 16 -> 4, clip ----
        float l0[4], l1[4];
        {
            const float4 gbq = *(const float4*)gb2;
            l0[0]=gbq.x; l0[1]=gbq.y; l0[2]=gbq.z; l0[3]=gbq.w;
            l1[0]=gbq.x; l1[1]=gbq.y; l1[2]=gbq.z; l1[3]=gbq.w;
            #pragma unroll
            for (int kk = 0; kk < 16; ++kk) {
                const float4 q = *(const float4*)(gw2 + kk*4);
                l0[0]=fmaf(g1a[kk],q.x,l0[0]); l1[0]=fmaf(g1b[kk],q.x,l1[0]);
                l0[1]=fmaf(g1a[kk],q.y,l0[1]); l1[1]=fmaf(g1b[kk],q.y,l1[1]);
                l0[2]=fmaf(g1a[kk],q.z,l0[2]); l1[2]=fmaf(g1b[kk],q.z,l1[2]);
                l0[3]=fmaf(g1a[kk],q.w,l0[3]); l1[3]=fmaf(g1b[kk],q.w,l1[3]);
            }
            #pragma unroll
            for (int w = 0; w < 4; ++w) {
                l0[w] = fminf(fmaxf(l0[w], -10.f), 10.f);
                l1[w] = fminf(fmaxf(l1[w], -10.f), 10.f);
            }
        }

        // ---- chunk masked max ----
        const float mk0 = mask_lds[r0], mk1 = mask_lds[r1];
        {
            float lm[4];
            #pragma unroll
            for (int w = 0; w < 4; ++w)
                lm[w] = fmaxf(mk0 > 0.f ? l0[w] : -1e30f,
                              mk1 > 0.f ? l1[w] : -1e30f);
            #pragma unroll
            for (int st = 32; st > 0; st >>= 1) {
                #pragma unroll
                for (int w = 0; w < 4; ++w)
                    lm[w] = fmaxf(lm[w], __shfl_xor(lm[w], st, 64));
            }
            if (lane == 0) {
                #pragma unroll
                for (int w = 0; w < 4; ++w) red_m[wv][w] = lm[w];
            }
        }
        __syncthreads();

        // ---- exp, p store, chunk sums ----
        {
            float ps[4];
            #pragma unroll
            for (int w = 0; w < 4; ++w) {
                const float mcw = fmaxf(fmaxf(red_m[0][w], red_m[1][w]),
                                        fmaxf(red_m[2][w], red_m[3][w]));
                const float p0 = mk0 * __expf(fminf(l0[w] - mcw, 0.f));
                const float p1 = mk1 * __expf(fminf(l1[w] - mcw, 0.f));
                if (sg == 0) { p_lds[r0][w] = p0; p_lds[r1][w] = p1; }
                ps[w] = (sg == 0) ? (p0 + p1) : 0.f;
            }
            #pragma unroll
            for (int st = 32; st > 0; st >>= 1) {
                #pragma unroll
                for (int w = 0; w < 4; ++w) ps[w] += __shfl_xor(ps[w], st, 64);
            }
            if (lane == 0) {
                #pragma unroll
                for (int w = 0; w < 4; ++w) red_s[wv][w] = ps[w];
            }
        }
        __syncthreads();

        // ---- weighted-sum accumulate with online-softmax merge ----
        {
            const float s_c = red_s[0][aw] + red_s[1][aw] + red_s[2][aw] + red_s[3][aw];
            const float mcw = fmaxf(fmaxf(red_m[0][aw], red_m[1][aw]),
                                    fmaxf(red_m[2][aw], red_m[3][aw]));
            const int rb = ahalf * 32;
            float dot = 0.f;
            #pragma unroll 8
            for (int rr = 0; rr < 32; ++rr)
                dot = fmaf(p_lds[rb+rr][aw], holds[rb+rr][ad], dot);
            dot += __shfl_xor(dot, 32, 64);
            const float mn = fmaxf(m_run, mcw);
            const float ea = __expf(m_run - mn);
            const float eb = __expf(mcw - mn);
            if (ahalf == 0) {
                accr  = fmaf(accr,  ea, dot * eb);
                s_run = fmaf(s_run, ea, s_c * eb);
                m_run = mn;
            }
        }
        __syncthreads();
    }

    if (ahalf == 0) {
        float* pp = part + (size_t)(b * NBLK + cb) * PART_STRIDE;
        if (ad == 0) { pp[aw] = m_run; pp[4 + aw] = s_run; }
        pp[8 + aw*32 + ad] = accr;
    }
}

// ---------------- Kernel 2: merge partials + per-batch encoder head ----------------
__global__ void pe_k2(const float* __restrict__ part,
                      const float* __restrict__ cw, const float* __restrict__ cb_,
                      const float* __restrict__ cg, const float* __restrict__ cbn,
                      const float* __restrict__ ew1, const float* __restrict__ eb1,
                      const float* __restrict__ eg1, const float* __restrict__ ebn1,
                      const float* __restrict__ ew2, const float* __restrict__ eb2,
                      const float* __restrict__ eg2, const float* __restrict__ ebn2,
                      float* __restrict__ out)
{
    const int b = blockIdx.x, tid = threadIdx.x;
    const int w = tid >> 5, d = tid & 31;
    __shared__ float hs[128];
    __shared__ float cbuf[32];
    __shared__ float ebuf[256];
    __shared__ float obuf[64];

    float m = -1e30f, s = 0.f, a = 0.f;
    for (int c = 0; c < NBLK; ++c) {
        const float* pp = part + (size_t)(b * NBLK + c) * PART_STRIDE;
        const float mc = pp[w], sc = pp[4 + w], ac = pp[8 + w*32 + d];
        const float mn = fmaxf(m, mc);
        const float e0 = __expf(m - mn), e1v = __expf(mc - mn);
        a = fmaf(a, e0, ac * e1v);
        s = fmaf(s, e0, sc * e1v);
        m = mn;
    }
    hs[w*32 + d] = a / fmaxf(s, 1e-30f);
    const bool has = (s > 0.f);
    __syncthreads();

    if (tid < 32) {
        float acc = cb_[tid];
        for (int k = 0; k < 128; ++k) acc = fmaf(hs[k], cw[k*32 + tid], acc);
        cbuf[tid] = acc;
    }
    __syncthreads();
    {
        float mu = 0.f, sq = 0.f;
        for (int k = 0; k < 32; ++k) { float v = cbuf[k]; mu += v; sq = fmaf(v, v, sq); }
        mu *= (1.f/32);
        float var = fmaxf(sq*(1.f/32) - mu*mu, 0.f);
        const float rs = rsqrtf(var + LN_EPS);
        __syncthreads();
        if (tid < 32) {
            float v = (cbuf[tid] - mu) * rs;
            v = fmaxf(fmaf(v, cg[tid], cbn[tid]), 0.f);
            cbuf[tid] = has ? v : 0.f;
        }
    }
    __syncthreads();

    #pragma unroll
    for (int r = 0; r < 2; ++r) {
        const int o = tid + r*128;
        float acc = eb1[o];
        for (int k = 0; k < 32; ++k) acc = fmaf(cbuf[k], ew1[k*EHH + o], acc);
        ebuf[o] = acc;
    }
    __syncthreads();
    {
        float mu = 0.f, sq = 0.f;
        for (int k = 0; k < 256; ++k) { float v = ebuf[k]; mu += v; sq = fmaf(v, v, sq); }
        mu *= (1.f/256);
        float var = fmaxf(sq*(1.f/256) - mu*mu, 0.f);
        const float rs = rsqrtf(var + LN_EPS);
        __syncthreads();
        #pragma unroll
        for (int r = 0; r < 2; ++r) {
            const int o = tid + r*128;
            float v = (ebuf[o] - mu) * rs;
            ebuf[o] = fmaxf(fmaf(v, eg1[o], ebn1[o]), 0.f);
        }
    }
    __syncthreads();

    if (tid < 64) {
        float acc = eb2[tid];
        for (int k = 0; k < 256; ++k) acc = fmaf(ebuf[k], ew2[k*64 + tid], acc);
        obuf[tid] = acc;
    }
    __syncthreads();
    {
        float mu = 0.f, sq = 0.f;
        for (int k = 0; k < 64; ++k) { float v = obuf[k]; mu += v; sq = fmaf(v, v, sq); }
        mu *= (1.f/64);
        float var = fmaxf(sq*(1.f/64) - mu*mu, 0.f);
        const float rs = rsqrtf(var + LN_EPS);
        if (tid < 64) {
            float v = (obuf[tid] - mu) * rs;
            v = fmaxf(fmaf(v, eg2[tid], ebn2[tid]), 0.f);
            if (tid < 32) out[(size_t)b*32 + tid] = v;
            else          out[(size_t)BB*32 + (size_t)b*32 + (tid-32)] = v;
        }
    }
}

extern "C" void kernel_launch(void* const* d_in, const int* in_sizes, int n_in,
                              void* d_out, int out_size, void* d_ws, size_t ws_size,
                              hipStream_t stream) {
    (void)in_sizes; (void)n_in; (void)out_size; (void)ws_size;
    const float* x     = (const float*)d_in[0];
    const int*   mask  = (const int*)  d_in[1];
    const float* feat  = (const float*)d_in[2];
    const float* h_w1  = (const float*)d_in[3];
    const float* h_b1  = (const float*)d_in[4];
    const float* h_l1g = (const float*)d_in[5];
    const float* h_l1b = (const float*)d_in[6];
    const float* h_w2  = (const float*)d_in[7];
    const float* h_b2  = (const float*)d_in[8];
    const float* h_l2g = (const float*)d_in[9];
    const float* h_l2b = (const float*)d_in[10];
    const float* g_w1  = (const float*)d_in[11];
    const float* g_b1  = (const float*)d_in[12];
    const float* g_w2  = (const float*)d_in[13];
    const float* g_b2  = (const float*)d_in[14];
    const float* c_w   = (const float*)d_in[15];
    const float* c_b   = (const float*)d_in[16];
    const float* c_lg  = (const float*)d_in[17];
    const float* c_lb  = (const float*)d_in[18];
    const float* e_w1  = (const float*)d_in[19];
    const float* e_b1  = (const float*)d_in[20];
    const float* e_l1g = (const float*)d_in[21];
    const float* e_l1b = (const float*)d_in[22];
    const float* e_w2  = (const float*)d_in[23];
    const float* e_b2  = (const float*)d_in[24];
    const float* e_l2g = (const float*)d_in[25];
    const float* e_l2b = (const float*)d_in[26];

    float* part = (float*)d_ws;
    float* out  = (float*)d_out;

    dim3 g1(NBLK, BB);
    pe_k1<<<g1, dim3(256), 0, stream>>>(x, mask, feat,
                                        h_w1, h_b1, h_l1g, h_l1b,
                                        h_w2, h_b2, h_l2g, h_l2b,
                                        g_w1, g_b1, g_w2, g_b2, part);
    pe_k2<<<dim3(BB), dim3(128), 0, stream>>>(part,
                                              c_w, c_b, c_lg, c_lb,
                                              e_w1, e_b1, e_l1g, e_l1b,
                                              e_w2, e_b2, e_l2g, e_l2b, out);
}

// Round 5
// 1186.506 us; speedup vs baseline: 5.2312x; 1.3406x over previous
//
#include <hip/hip_runtime.h>
#include <hip/hip_bf16.h>
#include <math.h>

#define BB 64
#define JJ 16384
#define DD 32
#define HH 128
#define WW 4
#define EHH 256
#define CHUNK 64
#define CPB 16
#define NBLK 16              /* JJ/(CHUNK*CPB) */
#define PART_STRIDE 136
#define LN_EPS 1e-5f

#define COMP(q,e) ((e)==0?(q).x:((e)==1?(q).y:((e)==2?(q).z:(q).w)))

// 8 FMAs x 4: weight quad feeds hb0/hb1[B..B+3] with row scalars f0,f1
#define S1Q(wq,B) \
  hb0[B+0]=fmaf((wq).x,f0,hb0[B+0]); hb1[B+0]=fmaf((wq).x,f1,hb1[B+0]); \
  hb0[B+1]=fmaf((wq).y,f0,hb0[B+1]); hb1[B+1]=fmaf((wq).y,f1,hb1[B+1]); \
  hb0[B+2]=fmaf((wq).z,f0,hb0[B+2]); hb1[B+2]=fmaf((wq).z,f1,hb1[B+2]); \
  hb0[B+3]=fmaf((wq).w,f0,hb0[B+3]); hb1[B+3]=fmaf((wq).w,f1,hb1[B+3]);

#define G1Q(Q,B) \
  g1a[B+0]=fmaf(h0v,(Q).x,g1a[B+0]); g1b[B+0]=fmaf(h1v,(Q).x,g1b[B+0]); \
  g1a[B+1]=fmaf(h0v,(Q).y,g1a[B+1]); g1b[B+1]=fmaf(h1v,(Q).y,g1b[B+1]); \
  g1a[B+2]=fmaf(h0v,(Q).z,g1a[B+2]); g1b[B+2]=fmaf(h1v,(Q).z,g1b[B+2]); \
  g1a[B+3]=fmaf(h0v,(Q).w,g1a[B+3]); g1b[B+3]=fmaf(h1v,(Q).w,g1b[B+3]);

// ---------------- Kernel 1 ----------------
// Thread (rg,sg): rg=tid>>3 owns rows 2rg,2rg+1; sg=tid&7 is the lane segment.
// Stage1: sg = 16-wide hidden segment (hb = 2x16 regs).
// Stage2: two K-halves through a per-wave-private LDS h buffer (float4,
//         (col4+rg)&15 rotation -> conflict-free b128 writes AND reads,
//         no barriers: hk rows are written and read by the same wave).
// Stage2 output: sg = 4-wide d segment; LN2/stage3/4 via 8-lane butterflies.
__launch_bounds__(256, 4)
__global__ void pe_k1(const float* __restrict__ x, const int* __restrict__ mask,
                      const float* __restrict__ feat,
                      const float* __restrict__ w1, const float* __restrict__ b1,
                      const float* __restrict__ ln1g, const float* __restrict__ ln1b,
                      const float* __restrict__ w2, const float* __restrict__ b2,
                      const float* __restrict__ ln2g, const float* __restrict__ ln2b,
                      const float* __restrict__ gw1, const float* __restrict__ gb1,
                      const float* __restrict__ gw2, const float* __restrict__ gb2,
                      float* __restrict__ part)
{
    const int tid = threadIdx.x;
    const int cb = blockIdx.x, b = blockIdx.y;
    const int rg = tid >> 3, sg = tid & 7;
    const int r0 = rg * 2, r1 = r0 + 1;
    const int wv = tid >> 6, lane = tid & 63;

    __shared__ float  in_lds[CHUNK][36];   // [row][0..31 feat | 32 x | 33 mask | pad]
    __shared__ float  holds[CHUNK][33];    // h_out per row (stride 33: 4-way max)
    __shared__ float4 hk4[CHUNK * 16];     // per-wave-private h half-K (16 KB)
    __shared__ float  p_lds[CHUNK][5];
    __shared__ float  red_m[4][4];
    __shared__ float  red_s[4][4];

    const int aw = tid >> 6, ahalf = (tid >> 5) & 1, ad = tid & 31;

    float m_run = -1e30f, s_run = 0.f, accr = 0.f;

    const float* w1s = w1 + sg * 16;

    for (int ch = 0; ch < CPB; ++ch) {
        const int jbase = (cb * CPB + ch) * CHUNK;

        // ---- stage inputs ----
        {
            const float4* fs = (const float4*)(feat + (size_t)jbase * 32);
            float4* in4 = (float4*)(&in_lds[0][0]);   // row stride = 9 float4
            #pragma unroll
            for (int i = 0; i < 2; ++i) {
                const int t = tid + i * 256;
                const float4 v = fs[t];
                in4[(t >> 3) * 9 + (t & 7)] = v;
            }
            if (tid < CHUNK)
                in_lds[tid][32] = x[(size_t)b * JJ + jbase + tid];
            else if (tid < 2 * CHUNK)
                in_lds[tid - CHUNK][33] =
                    mask[(size_t)b * JJ + jbase + (tid - CHUNK)] ? 1.f : 0.f;
        }
        __syncthreads();

        // ---- stage 1: (1+32) -> hidden[sg*16 .. +15] for rows r0,r1 ----
        float hb0[16], hb1[16];
        {
            const float xin0 = in_lds[r0][32], xin1 = in_lds[r1][32];
            #pragma unroll
            for (int q4 = 0; q4 < 4; ++q4) {
                const float4 bq = *(const float4*)(b1 + sg*16 + q4*4);
                const float4 wq = *(const float4*)(w1s + q4*4);   // w1 row 0 (x)
                hb0[q4*4+0]=fmaf(wq.x,xin0,bq.x); hb1[q4*4+0]=fmaf(wq.x,xin1,bq.x);
                hb0[q4*4+1]=fmaf(wq.y,xin0,bq.y); hb1[q4*4+1]=fmaf(wq.y,xin1,bq.y);
                hb0[q4*4+2]=fmaf(wq.z,xin0,bq.z); hb1[q4*4+2]=fmaf(wq.z,xin1,bq.z);
                hb0[q4*4+3]=fmaf(wq.w,xin0,bq.w); hb1[q4*4+3]=fmaf(wq.w,xin1,bq.w);
            }
        }
        #pragma unroll 4
        for (int tt = 0; tt < 8; ++tt) {
            const float4 f0q = *(const float4*)(&in_lds[r0][tt*4]);
            const float4 f1q = *(const float4*)(&in_lds[r1][tt*4]);
            #pragma unroll
            for (int e = 0; e < 4; ++e) {
                const float f0 = COMP(f0q, e), f1 = COMP(f1q, e);
                const float* wr = w1s + (tt*4 + e + 1) * HH;
                const float4 q0 = *(const float4*)(wr);
                const float4 q1 = *(const float4*)(wr + 4);
                const float4 q2 = *(const float4*)(wr + 8);
                const float4 q3 = *(const float4*)(wr + 12);
                S1Q(q0,0) S1Q(q1,4) S1Q(q2,8) S1Q(q3,12)
            }
        }
        // ---- LN1 + relu (8-lane butterfly), result stays in hb ----
        {
            float s0=0.f,q0=0.f,s1=0.f,q1=0.f;
            #pragma unroll
            for (int o = 0; o < 16; ++o) {
                s0 += hb0[o]; q0 = fmaf(hb0[o],hb0[o],q0);
                s1 += hb1[o]; q1 = fmaf(hb1[o],hb1[o],q1);
            }
            #pragma unroll
            for (int st = 1; st < 8; st <<= 1) {
                s0 += __shfl_xor(s0, st, 64); q0 += __shfl_xor(q0, st, 64);
                s1 += __shfl_xor(s1, st, 64); q1 += __shfl_xor(q1, st, 64);
            }
            const float mu0 = s0 * (1.f/HH);
            const float rs0 = rsqrtf(fmaxf(q0*(1.f/HH) - mu0*mu0, 0.f) + LN_EPS);
            const float mu1 = s1 * (1.f/HH);
            const float rs1 = rsqrtf(fmaxf(q1*(1.f/HH) - mu1*mu1, 0.f) + LN_EPS);
            #pragma unroll
            for (int q4 = 0; q4 < 4; ++q4) {
                const float4 gq = *(const float4*)(ln1g + sg*16 + q4*4);
                const float4 tq = *(const float4*)(ln1b + sg*16 + q4*4);
                hb0[q4*4+0]=fmaxf(fmaf((hb0[q4*4+0]-mu0)*rs0, gq.x, tq.x),0.f);
                hb0[q4*4+1]=fmaxf(fmaf((hb0[q4*4+1]-mu0)*rs0, gq.y, tq.y),0.f);
                hb0[q4*4+2]=fmaxf(fmaf((hb0[q4*4+2]-mu0)*rs0, gq.z, tq.z),0.f);
                hb0[q4*4+3]=fmaxf(fmaf((hb0[q4*4+3]-mu0)*rs0, gq.w, tq.w),0.f);
                hb1[q4*4+0]=fmaxf(fmaf((hb1[q4*4+0]-mu1)*rs1, gq.x, tq.x),0.f);
                hb1[q4*4+1]=fmaxf(fmaf((hb1[q4*4+1]-mu1)*rs1, gq.y, tq.y),0.f);
                hb1[q4*4+2]=fmaxf(fmaf((hb1[q4*4+2]-mu1)*rs1, gq.z, tq.z),0.f);
                hb1[q4*4+3]=fmaxf(fmaf((hb1[q4*4+3]-mu1)*rs1, gq.w, tq.w),0.f);
            }
        }

        // ---- stage 2: h(128) @ w2 -> d[sg*4 .. +3], two K-halves via hk4 ----
        float ac0[4] = {0.f,0.f,0.f,0.f}, ac1[4] = {0.f,0.f,0.f,0.f};
        #pragma unroll
        for (int hf2 = 0; hf2 < 2; ++hf2) {
            if ((sg >> 2) == hf2) {                 // owners publish this half
                const int sgl = sg & 3;
                #pragma unroll
                for (int o4 = 0; o4 < 4; ++o4) {
                    const int p = (sgl*4 + o4 + rg) & 15;
                    hk4[r0*16 + p] = make_float4(hb0[o4*4],hb0[o4*4+1],hb0[o4*4+2],hb0[o4*4+3]);
                    hk4[r1*16 + p] = make_float4(hb1[o4*4],hb1[o4*4+1],hb1[o4*4+2],hb1[o4*4+3]);
                }
            }
            // same-wave producer/consumer: DS pipe is in-order, no barrier
            const float* w2h = w2 + hf2*64*DD + sg*4;
            #pragma unroll 4
            for (int L = 0; L < 16; ++L) {
                const int p = (L + rg) & 15;
                const float4 h0q = hk4[r0*16 + p];
                const float4 h1q = hk4[r1*16 + p];
                #pragma unroll
                for (int e = 0; e < 4; ++e) {
                    const float4 wq = *(const float4*)(w2h + (L*4+e)*DD);
                    const float h0 = COMP(h0q,e), h1 = COMP(h1q,e);
                    ac0[0]=fmaf(h0,wq.x,ac0[0]); ac1[0]=fmaf(h1,wq.x,ac1[0]);
                    ac0[1]=fmaf(h0,wq.y,ac0[1]); ac1[1]=fmaf(h1,wq.y,ac1[1]);
                    ac0[2]=fmaf(h0,wq.z,ac0[2]); ac1[2]=fmaf(h1,wq.z,ac1[2]);
                    ac0[3]=fmaf(h0,wq.w,ac0[3]); ac1[3]=fmaf(h1,wq.w,ac1[3]);
                }
            }
        }
        {
            const float4 bq = *(const float4*)(b2 + sg*4);
            ac0[0]+=bq.x; ac0[1]+=bq.y; ac0[2]+=bq.z; ac0[3]+=bq.w;
            ac1[0]+=bq.x; ac1[1]+=bq.y; ac1[2]+=bq.z; ac1[3]+=bq.w;
        }
        // ---- LN2 + relu ----
        float ho0[4], ho1[4];
        {
            float s0 = ac0[0]+ac0[1]+ac0[2]+ac0[3];
            float s1 = ac1[0]+ac1[1]+ac1[2]+ac1[3];
            float q0 = ac0[0]*ac0[0]+ac0[1]*ac0[1]+ac0[2]*ac0[2]+ac0[3]*ac0[3];
            float q1 = ac1[0]*ac1[0]+ac1[1]*ac1[1]+ac1[2]*ac1[2]+ac1[3]*ac1[3];
            #pragma unroll
            for (int st = 1; st < 8; st <<= 1) {
                s0 += __shfl_xor(s0, st, 64); q0 += __shfl_xor(q0, st, 64);
                s1 += __shfl_xor(s1, st, 64); q1 += __shfl_xor(q1, st, 64);
            }
            const float mu0 = s0 * (1.f/DD);
            const float rs0 = rsqrtf(fmaxf(q0*(1.f/DD) - mu0*mu0, 0.f) + LN_EPS);
            const float mu1 = s1 * (1.f/DD);
            const float rs1 = rsqrtf(fmaxf(q1*(1.f/DD) - mu1*mu1, 0.f) + LN_EPS);
            const float4 gq = *(const float4*)(ln2g + sg*4);
            const float4 tq = *(const float4*)(ln2b + sg*4);
            ho0[0]=fmaxf(fmaf((ac0[0]-mu0)*rs0, gq.x, tq.x),0.f);
            ho0[1]=fmaxf(fmaf((ac0[1]-mu0)*rs0, gq.y, tq.y),0.f);
            ho0[2]=fmaxf(fmaf((ac0[2]-mu0)*rs0, gq.z, tq.z),0.f);
            ho0[3]=fmaxf(fmaf((ac0[3]-mu0)*rs0, gq.w, tq.w),0.f);
            ho1[0]=fmaxf(fmaf((ac1[0]-mu1)*rs1, gq.x, tq.x),0.f);
            ho1[1]=fmaxf(fmaf((ac1[1]-mu1)*rs1, gq.y, tq.y),0.f);
            ho1[2]=fmaxf(fmaf((ac1[2]-mu1)*rs1, gq.z, tq.z),0.f);
            ho1[3]=fmaxf(fmaf((ac1[3]-mu1)*rs1, gq.w, tq.w),0.f);
            #pragma unroll
            for (int i = 0; i < 4; ++i) {
                holds[r0][sg*4+i] = ho0[i];
                holds[r1][sg*4+i] = ho1[i];
            }
        }

        // ---- stage 3: 32 -> 16 (partials over own 4 k, butterfly sum) ----
        float g1a[16], g1b[16];
        #pragma unroll
        for (int o = 0; o < 16; ++o) { g1a[o]=0.f; g1b[o]=0.f; }
        #pragma unroll
        for (int kk = 0; kk < 4; ++kk) {
            const float h0v = ho0[kk], h1v = ho1[kk];
            const float* gr = gw1 + (sg*4+kk)*16;
            const float4 p0 = *(const float4*)(gr);
            const float4 p1 = *(const float4*)(gr + 4);
            const float4 p2 = *(const float4*)(gr + 8);
            const float4 p3 = *(const float4*)(gr + 12);
            G1Q(p0,0) G1Q(p1,4) G1Q(p2,8) G1Q(p3,12)
        }
        #pragma unroll
        for (int st = 1; st < 8; st <<= 1) {
            #pragma unroll
            for (int o = 0; o < 16; ++o) {
                g1a[o] += __shfl_xor(g1a[o], st, 64);
                g1b[o] += __shfl_xor(g1b[o], st, 64);
            }
        }
        #pragma unroll
        for (int o = 0; o < 16; ++o) {
            g1a[o] = fmaxf(g1a[o] + gb1[o], 0.f);
            g1b[o] = fmaxf(g1b[o] + gb1[o], 0.f);
        }

        // ---- stage 4: 16 -> 4, clip ----
        float l0[4], l1[4];
        {
            const float4 gbq = *(const float4*)gb2;
            l0[0]=gbq.x; l0[1]=gbq.y; l0[2]=gbq.z; l0[3]=gbq.w;
            l1[0]=gbq.x; l1[1]=gbq.y; l1[2]=gbq.z; l1[3]=gbq.w;
            #pragma unroll
            for (int kk = 0; kk < 16; ++kk) {
                const float4 q = *(const float4*)(gw2 + kk*4);
                l0[0]=fmaf(g1a[kk],q.x,l0[0]); l1[0]=fmaf(g1b[kk],q.x,l1[0]);
                l0[1]=fmaf(g1a[kk],q.y,l0[1]); l1[1]=fmaf(g1b[kk],q.y,l1[1]);
                l0[2]=fmaf(g1a[kk],q.z,l0[2]); l1[2]=fmaf(g1b[kk],q.z,l1[2]);
                l0[3]=fmaf(g1a[kk],q.w,l0[3]); l1[3]=fmaf(g1b[kk],q.w,l1[3]);
            }
            #pragma unroll
            for (int w = 0; w < 4; ++w) {
                l0[w] = fminf(fmaxf(l0[w], -10.f), 10.f);
                l1[w] = fminf(fmaxf(l1[w], -10.f), 10.f);
            }
        }

        // ---- chunk masked max ----
        const float mk0 = in_lds[r0][33], mk1 = in_lds[r1][33];
        {
            float lm[4];
            #pragma unroll
            for (int w = 0; w < 4; ++w)
                lm[w] = fmaxf(mk0 > 0.f ? l0[w] : -1e30f,
                              mk1 > 0.f ? l1[w] : -1e30f);
            #pragma unroll
            for (int st = 32; st > 0; st >>= 1) {
                #pragma unroll
                for (int w = 0; w < 4; ++w)
                    lm[w] = fmaxf(lm[w], __shfl_xor(lm[w], st, 64));
            }
            if (lane == 0) {
                #pragma unroll
                for (int w = 0; w < 4; ++w) red_m[wv][w] = lm[w];
            }
        }
        __syncthreads();

        // ---- exp, p store, chunk sums ----
        {
            float ps[4];
            #pragma unroll
            for (int w = 0; w < 4; ++w) {
                const float mcw = fmaxf(fmaxf(red_m[0][w], red_m[1][w]),
                                        fmaxf(red_m[2][w], red_m[3][w]));
                const float p0 = mk0 * __expf(fminf(l0[w] - mcw, 0.f));
                const float p1 = mk1 * __expf(fminf(l1[w] - mcw, 0.f));
                if (sg == 0) { p_lds[r0][w] = p0; p_lds[r1][w] = p1; }
                ps[w] = (sg == 0) ? (p0 + p1) : 0.f;
            }
            #pragma unroll
            for (int st = 32; st > 0; st >>= 1) {
                #pragma unroll
                for (int w = 0; w < 4; ++w) ps[w] += __shfl_xor(ps[w], st, 64);
            }
            if (lane == 0) {
                #pragma unroll
                for (int w = 0; w < 4; ++w) red_s[wv][w] = ps[w];
            }
        }
        __syncthreads();

        // ---- weighted-sum accumulate with online-softmax merge ----
        {
            const float s_c = red_s[0][aw] + red_s[1][aw] + red_s[2][aw] + red_s[3][aw];
            const float mcw = fmaxf(fmaxf(red_m[0][aw], red_m[1][aw]),
                                    fmaxf(red_m[2][aw], red_m[3][aw]));
            const int rb = ahalf * 32;
            float dot = 0.f;
            #pragma unroll 8
            for (int rr = 0; rr < 32; ++rr)
                dot = fmaf(p_lds[rb+rr][aw], holds[rb+rr][ad], dot);
            dot += __shfl_xor(dot, 32, 64);
            const float mn = fmaxf(m_run, mcw);
            const float ea = __expf(m_run - mn);
            const float eb = __expf(mcw - mn);
            if (ahalf == 0) {
                accr  = fmaf(accr,  ea, dot * eb);
                s_run = fmaf(s_run, ea, s_c * eb);
                m_run = mn;
            }
        }
        __syncthreads();
    }

    if (ahalf == 0) {
        float* pp = part + (size_t)(b * NBLK + cb) * PART_STRIDE;
        if (ad == 0) { pp[aw] = m_run; pp[4 + aw] = s_run; }
        pp[8 + aw*32 + ad] = accr;
    }
}

// ---------------- Kernel 2: merge partials + per-batch encoder head ----------------
__global__ void pe_k2(const float* __restrict__ part,
                      const float* __restrict__ cw, const float* __restrict__ cb_,
                      const float* __restrict__ cg, const float* __restrict__ cbn,
                      const float* __restrict__ ew1, const float* __restrict__ eb1,
                      const float* __restrict__ eg1, const float* __restrict__ ebn1,
                      const float* __restrict__ ew2, const float* __restrict__ eb2,
                      const float* __restrict__ eg2, const float* __restrict__ ebn2,
                      float* __restrict__ out)
{
    const int b = blockIdx.x, tid = threadIdx.x;
    const int w = tid >> 5, d = tid & 31;
    __shared__ float hs[128];
    __shared__ float cbuf[32];
    __shared__ float ebuf[256];
    __shared__ float obuf[64];

    float m = -1e30f, s = 0.f, a = 0.f;
    for (int c = 0; c < NBLK; ++c) {
        const float* pp = part + (size_t)(b * NBLK + c) * PART_STRIDE;
        const float mc = pp[w], sc = pp[4 + w], ac = pp[8 + w*32 + d];
        const float mn = fmaxf(m, mc);
        const float e0 = __expf(m - mn), e1v = __expf(mc - mn);
        a = fmaf(a, e0, ac * e1v);
        s = fmaf(s, e0, sc * e1v);
        m = mn;
    }
    hs[w*32 + d] = a / fmaxf(s, 1e-30f);
    const bool has = (s > 0.f);
    __syncthreads();

    if (tid < 32) {
        float acc = cb_[tid];
        for (int k = 0; k < 128; ++k) acc = fmaf(hs[k], cw[k*32 + tid], acc);
        cbuf[tid] = acc;
    }
    __syncthreads();
    {
        float mu = 0.f, sq = 0.f;
        for (int k = 0; k < 32; ++k) { float v = cbuf[k]; mu += v; sq = fmaf(v, v, sq); }
        mu *= (1.f/32);
        float var = fmaxf(sq*(1.f/32) - mu*mu, 0.f);
        const float rs = rsqrtf(var + LN_EPS);
        __syncthreads();
        if (tid < 32) {
            float v = (cbuf[tid] - mu) * rs;
            v = fmaxf(fmaf(v, cg[tid], cbn[tid]), 0.f);
            cbuf[tid] = has ? v : 0.f;
        }
    }
    __syncthreads();

    #pragma unroll
    for (int r = 0; r < 2; ++r) {
        const int o = tid + r*128;
        float acc = eb1[o];
        for (int k = 0; k < 32; ++k) acc = fmaf(cbuf[k], ew1[k*EHH + o], acc);
        ebuf[o] = acc;
    }
    __syncthreads();
    {
        float mu = 0.f, sq = 0.f;
        for (int k = 0; k < 256; ++k) { float v = ebuf[k]; mu += v; sq = fmaf(v, v, sq); }
        mu *= (1.f/256);
        float var = fmaxf(sq*(1.f/256) - mu*mu, 0.f);
        const float rs = rsqrtf(var + LN_EPS);
        __syncthreads();
        #pragma unroll
        for (int r = 0; r < 2; ++r) {
            const int o = tid + r*128;
            float v = (ebuf[o] - mu) * rs;
            ebuf[o] = fmaxf(fmaf(v, eg1[o], ebn1[o]), 0.f);
        }
    }
    __syncthreads();

    if (tid < 64) {
        float acc = eb2[tid];
        for (int k = 0; k < 256; ++k) acc = fmaf(ebuf[k], ew2[k*64 + tid], acc);
        obuf[tid] = acc;
    }
    __syncthreads();
    {
        float mu = 0.f, sq = 0.f;
        for (int k = 0; k < 64; ++k) { float v = obuf[k]; mu += v; sq = fmaf(v, v, sq); }
        mu *= (1.f/64);
        float var = fmaxf(sq*(1.f/64) - mu*mu, 0.f);
        const float rs = rsqrtf(var + LN_EPS);
        if (tid < 64) {
            float v = (obuf[tid] - mu) * rs;
            v = fmaxf(fmaf(v, eg2[tid], ebn2[tid]), 0.f);
            if (tid < 32) out[(size_t)b*32 + tid] = v;
            else          out[(size_t)BB*32 + (size_t)b*32 + (tid-32)] = v;
        }
    }
}

extern "C" void kernel_launch(void* const* d_in, const int* in_sizes, int n_in,
                              void* d_out, int out_size, void* d_ws, size_t ws_size,
                              hipStream_t stream) {
    (void)in_sizes; (void)n_in; (void)out_size; (void)ws_size;
    const float* x     = (const float*)d_in[0];
    const int*   mask  = (const int*)  d_in[1];
    const float* feat  = (const float*)d_in[2];
    const float* h_w1  = (const float*)d_in[3];
    const float* h_b1  = (const float*)d_in[4];
    const float* h_l1g = (const float*)d_in[5];
    const float* h_l1b = (const float*)d_in[6];
    const float* h_w2  = (const float*)d_in[7];
    const float* h_b2  = (const float*)d_in[8];
    const float* h_l2g = (const float*)d_in[9];
    const float* h_l2b = (const float*)d_in[10];
    const float* g_w1  = (const float*)d_in[11];
    const float* g_b1  = (const float*)d_in[12];
    const float* g_w2  = (const float*)d_in[13];
    const float* g_b2  = (const float*)d_in[14];
    const float* c_w   = (const float*)d_in[15];
    const float* c_b   = (const float*)d_in[16];
    const float* c_lg  = (const float*)d_in[17];
    const float* c_lb  = (const float*)d_in[18];
    const float* e_w1  = (const float*)d_in[19];
    const float* e_b1  = (const float*)d_in[20];
    const float* e_l1g = (const float*)d_in[21];
    const float* e_l1b = (const float*)d_in[22];
    const float* e_w2  = (const float*)d_in[23];
    const float* e_b2  = (const float*)d_in[24];
    const float* e_l2g = (const float*)d_in[25];
    const float* e_l2b = (const float*)d_in[26];

    float* part = (float*)d_ws;
    float* out  = (float*)d_out;

    dim3 g1(NBLK, BB);
    pe_k1<<<g1, dim3(256), 0, stream>>>(x, mask, feat,
                                        h_w1, h_b1, h_l1g, h_l1b,
                                        h_w2, h_b2, h_l2g, h_l2b,
                                        g_w1, g_b1, g_w2, g_b2, part);
    pe_k2<<<dim3(BB), dim3(128), 0, stream>>>(part,
                                              c_w, c_b, c_lg, c_lb,
                                              e_w1, e_b1, e_l1g, e_l1b,
                                              e_w2, e_b2, e_l2g, e_l2b, out);
}